// Round 10
// baseline (556.003 us; speedup 1.0000x reference)
//
#include <hip/hip_runtime.h>

#define NN   1000
#define EE   16000
#define FF   64
#define SS   192
#define TNF  768000
#define NB   16
#define NC   10
#define LWG2 1024  // k_lin_chunk grid (4 blocks/CU)
#define EPAD 24576 // padded edge-list capacity (sum ceil(deg/8)*8 <= 23000)

typedef unsigned short u16;
typedef unsigned int   u32;
typedef float f32x4_t __attribute__((ext_vector_type(4)));
typedef short s16x4_t __attribute__((ext_vector_type(4)));
typedef short s16x8_t __attribute__((ext_vector_type(8)));
typedef _Float16 f16x2_t __attribute__((ext_vector_type(2)));
typedef _Float16 f16x8_t __attribute__((ext_vector_type(8)));

__device__ __forceinline__ float bf2f(u16 u) {
    return __uint_as_float(((u32)u) << 16);
}
__device__ __forceinline__ u16 f2bf(float f) {
    u32 u = __float_as_uint(f);
    u32 r = u + 0x7FFFu + ((u >> 16) & 1u);
    return (u16)(r >> 16);
}
__device__ __forceinline__ u16 f2h(float f) {
    _Float16 h = (_Float16)f;   // v_cvt_f16_f32 (RNE)
    return __builtin_bit_cast(unsigned short, h);
}
// flag-dispatched scalar float load (f32m: 1 = fp32 array, 0 = bf16 array)
__device__ __forceinline__ float ldf(const void* p, size_t i, int f32m) {
    return f32m ? ((const float*)p)[i] : bf2f(((const u16*)p)[i]);
}

// pack float4 -> 4 f16 in a uint2
__device__ __forceinline__ uint2 pk4h(float4 v) {
    uint2 p;
    p.x = (u32)f2h(v.x) | ((u32)f2h(v.y) << 16);
    p.y = (u32)f2h(v.z) | ((u32)f2h(v.w) << 16);
    return p;
}

// async global->LDS 16B copy (dest must be wave-uniform base + lane*16)
__device__ __forceinline__ void gl_lds16(const void* src, void* dst) {
    __builtin_amdgcn_global_load_lds(
        (const __attribute__((address_space(1))) unsigned int*)src,
        (__attribute__((address_space(3))) unsigned int*)dst, 16, 0, 0);
}

// ---------------- merged prep: detect + zero + edge-list prefill ----------------
// edge lists hold BYTE offsets (idx*8); dummy = 1000*8 = 8000 = 0x1F40
__global__ void k_pre(const u16* __restrict__ x, const int* __restrict__ ei,
                      int* __restrict__ flags, int* __restrict__ ints,
                      float* __restrict__ obuf, u16* __restrict__ eo_s,
                      u16* __restrict__ eid_s) {
    const int i = blockIdx.x * 256 + threadIdx.x;
    if (blockIdx.x == 0 && threadIdx.x < 64) {   // wave 0: parallel dtype detect
        const int lane = threadIdx.x;
        u16 u1 = x[2 * lane], u2 = x[2 * (lane + 64)];
        int e1 = (u1 >> 7) & 0xFF, e2 = (u2 >> 7) & 0xFF;
        int ok1 = (u1 == 0 || (e1 >= 100 && e1 <= 140)) ? 1 : 0;
        int ok2 = (u2 == 0 || (e2 >= 100 && e2 <= 140)) ? 1 : 0;
        unsigned long long b1 = __ballot(ok1), b2 = __ballot(ok2);
        int nzf = (lane < 32 && ei[2 * lane + 1] != 0) ? 1 : 0;
        unsigned long long b3 = __ballot(nzf);
        if (lane == 0) {
            int good = __popcll(b1) + __popcll(b2);
            flags[0] = (good < 96) ? 1 : 0;           // <75% plausible -> fp32
            flags[1] = (__popcll(b3) <= 4) ? 1 : 0;   // odd words all zero -> int64
        }
    }
    if (i < 4000) ints[i] = 0;
    if (i < 160) obuf[i] = 0.f;
    if (i < EPAD / 2) {
        ((u32*)eo_s)[i] = 0x1F401F40u;
        ((u32*)eid_s)[i] = 0x1F401F40u;
    }
}

__global__ void k_deg(const int* __restrict__ ei, int* __restrict__ deg,
                      const int* __restrict__ flags) {
    int e = blockIdx.x * 256 + threadIdx.x;
    const int sh = flags[1];
    if (e < EE) {
        int r = ei[(size_t)e << sh];
        int c = ei[(size_t)(EE + e) << sh];
        atomicAdd(&deg[r & 1023], 1);
        atomicAdd(&deg[NN + (c & 1023)], 1);
    }
}

// 8-padded CSR offsets + inverse degrees
__global__ __launch_bounds__(1024) void k_scan(const int* __restrict__ deg_in,
        const int* __restrict__ deg_out, int* __restrict__ ooffp, int* __restrict__ ioffp,
        float* __restrict__ inv_o, float* __restrict__ inv_i) {
    __shared__ int sa[1024], sb2[1024];
    const int t = threadIdx.x;
    for (int pass = 0; pass < 2; ++pass) {
        const int* deg = pass ? deg_out : deg_in;
        int* dst_off = pass ? ioffp : ooffp;
        sa[t] = (t < NN) ? ((deg[t] + 7) & ~7) : 0;
        __syncthreads();
        int* src = sa; int* dst = sb2;
        for (int offn = 1; offn < 1024; offn <<= 1) {
            int v = src[t];
            if (t >= offn) v += src[t - offn];
            dst[t] = v;
            __syncthreads();
            int* tmp = src; src = dst; dst = tmp;
        }
        if (t == 0) dst_off[0] = 0;
        if (t < NN) dst_off[t + 1] = src[t];
        __syncthreads();
    }
    if (t < NN) {
        inv_o[t] = 1.0f / (float)max(deg_out[t], 1);
        inv_i[t] = 1.0f / (float)max(deg_in[t], 1);
    }
}

__global__ void k_fill(const int* __restrict__ ei, const int* __restrict__ ooffp,
        const int* __restrict__ ioffp, int* __restrict__ cur,
        u16* __restrict__ eo_s, u16* __restrict__ eid_s,
        const int* __restrict__ flags) {
    int e = blockIdx.x * 256 + threadIdx.x;
    const int sh = flags[1];
    if (e < EE) {
        int r = ei[(size_t)e << sh] & 1023;
        int c = ei[(size_t)(EE + e) << sh] & 1023;
        int po = ooffp[c] + atomicAdd(&cur[c], 1);       // group by dst
        eo_s[po] = (u16)(r * 8);                          // byte offset
        int pi = ioffp[r] + atomicAdd(&cur[NN + r], 1);  // group by src
        eid_s[pi] = (u16)(c * 8);
    }
}

// Wt[col][kappa] (f16), kappa = j*64 + fi.  col<64 -> z (W_z), col>=64 -> h (W_h).
__global__ void k_wt(const void* __restrict__ Wz, const void* __restrict__ Wh,
                     u16* __restrict__ wt, const int* __restrict__ flags) {
    int idx = blockIdx.x * 256 + threadIdx.x;
    if (idx >= 128 * 576) return;
    const int f32m = flags[0];
    const int col = idx / 576;
    const int kk = idx - col * 576;
    const int j = kk >> 6, fi = kk & 63;
    const void* W = (col < 64) ? Wz : Wh;
    const int fo = col & 63;
    float v;
    if (j == 0) {
        v = ldf(W, (size_t)(0 * 128 + fi) * 64 + fo, f32m)
          + ldf(W, (size_t)(5 * 128 + fi) * 64 + fo, f32m);
    } else {
        const int d = (j & 1) ? 0 : 1;
        const int kq = (j + 1) >> 1;
        v = ldf(W, (size_t)((d * 5 + kq) * 128 + fi) * 64 + fo, f32m);
    }
    wt[col * 576 + kk] = f2h(v);
}

// ---------------- phase 1: Chebyshev basis (UNCHANGED source — control) ----------------
// basis: [sb(16)][j(9)][row(rchp)][f4(4)] f16

__device__ __forceinline__ float4 g8h(const char* __restrict__ S,
                                      const u16* __restrict__ lst, int e0, int e1) {
    f16x2_t a0 = {(_Float16)0, (_Float16)0}, a1 = a0, b0 = a0, b1 = a0;
    for (int e = e0; e < e1; e += 8) {
        uint4 w = *(const uint4*)(lst + e);   // 8 u16 byte-offsets, 16B aligned
        int i0 = w.x & 0xFFFF, i1 = w.x >> 16;
        int i2 = w.y & 0xFFFF, i3 = w.y >> 16;
        int i4 = w.z & 0xFFFF, i5 = w.z >> 16;
        int i6 = w.w & 0xFFFF, i7 = w.w >> 16;
        uint2 q0 = *(const uint2*)(S + i0), q1 = *(const uint2*)(S + i1);
        uint2 q2 = *(const uint2*)(S + i2), q3 = *(const uint2*)(S + i3);
        uint2 q4 = *(const uint2*)(S + i4), q5 = *(const uint2*)(S + i5);
        uint2 q6 = *(const uint2*)(S + i6), q7 = *(const uint2*)(S + i7);
        a0 += __builtin_bit_cast(f16x2_t, q0.x); a1 += __builtin_bit_cast(f16x2_t, q0.y);
        b0 += __builtin_bit_cast(f16x2_t, q1.x); b1 += __builtin_bit_cast(f16x2_t, q1.y);
        a0 += __builtin_bit_cast(f16x2_t, q2.x); a1 += __builtin_bit_cast(f16x2_t, q2.y);
        b0 += __builtin_bit_cast(f16x2_t, q3.x); b1 += __builtin_bit_cast(f16x2_t, q3.y);
        a0 += __builtin_bit_cast(f16x2_t, q4.x); a1 += __builtin_bit_cast(f16x2_t, q4.y);
        b0 += __builtin_bit_cast(f16x2_t, q5.x); b1 += __builtin_bit_cast(f16x2_t, q5.y);
        a0 += __builtin_bit_cast(f16x2_t, q6.x); a1 += __builtin_bit_cast(f16x2_t, q6.y);
        b0 += __builtin_bit_cast(f16x2_t, q7.x); b1 += __builtin_bit_cast(f16x2_t, q7.y);
    }
    float4 r;
    r.x = (float)a0.x + (float)b0.x;
    r.y = (float)a0.y + (float)b0.y;
    r.z = (float)a1.x + (float)b1.x;
    r.w = (float)a1.y + (float)b1.y;
    return r;
}

__global__ __launch_bounds__(1024) void k_cheb(const void* __restrict__ xv_,
        const u16* __restrict__ eo_s, const int* __restrict__ ooffp,
        const u16* __restrict__ eid_s, const int* __restrict__ ioffp,
        const float* __restrict__ inv_o, const float* __restrict__ inv_i,
        u16* __restrict__ basis, int s0, int rchp,
        const int* __restrict__ flags, int chs) {
    __shared__ uint2 bXo[1024], bXi[1024], bA[1024], bB[1024];
    const int sb = blockIdx.x / chs;
    const int slocal = blockIdx.x - sb * chs;
    const int s = s0 + slocal;
    const int n = threadIdx.x;
    const bool act = (n < NN);
    const int f32m = flags[0];
    int e0o = 0, e1o = 0, e0i = 0, e1i = 0;
    float fiv = 0.f, fov = 0.f;
    const int row = slocal * NN + n;
    if (act) {
        e0o = ooffp[n]; e1o = ooffp[n + 1];
        e0i = ioffp[n]; e1i = ioffp[n + 1];
        fiv = inv_i[n];
        fov = inv_o[n];
    }
    const float fiv2 = 2.f * fiv;
    u16* const bp = basis + (size_t)(sb * 9) * rchp * 4 + (size_t)row * 4;
    const size_t jstep = (size_t)rchp * 4;   // u16s per j-plane
    float4 rx, rt1o, rt2o;
    if (n >= NN) {   // zero the dummy slots (1000..1023) in all buffers
        const uint2 z = make_uint2(0u, 0u);
        bXo[n] = z; bXi[n] = z; bA[n] = z; bB[n] = z;
    }
    if (act) {
        const size_t xoff = ((size_t)s * NN + n) * FF + sb * 4;
        if (f32m) {
            rx = *(const float4*)((const float*)xv_ + xoff);
        } else {
            ushort4 u = *(const ushort4*)((const u16*)xv_ + xoff);
            rx = make_float4(bf2f(u.x), bf2f(u.y), bf2f(u.z), bf2f(u.w));
        }
        bXi[n] = pk4h(rx);
        bXo[n] = pk4h(make_float4(fov * rx.x, fov * rx.y, fov * rx.z, fov * rx.w));
        *(uint2*)bp = pk4h(rx);                          // j0 raw
    }
    __syncthreads();
    // ph12: T1o = sum(bXo) ; T1i = fiv * sum(bXi)
    if (act) {
        float4 go = g8h((const char*)bXo, eo_s, e0o, e1o);
        float4 gi = g8h((const char*)bXi, eid_s, e0i, e1i);
        rt1o = go;
        bA[n] = pk4h(make_float4(fov * go.x, fov * go.y, fov * go.z, fov * go.w));
        *(uint2*)(bp + jstep) = pk4h(go);                // j1 raw
        float4 t = make_float4(gi.x * fiv, gi.y * fiv, gi.z * fiv, gi.w * fiv);
        bB[n] = pk4h(t);
        *(uint2*)(bp + 2 * jstep) = pk4h(t);             // j2 raw
    }
    __syncthreads();
    // ph34: T2o = 2*sum(bA) - x ; T2i = fiv2*sum(bB) - x
    if (act) {
        float4 go = g8h((const char*)bA, eo_s, e0o, e1o);
        float4 gi = g8h((const char*)bB, eid_s, e0i, e1i);
        float4 t2o = make_float4(fmaf(2.f, go.x, -rx.x), fmaf(2.f, go.y, -rx.y),
                                 fmaf(2.f, go.z, -rx.z), fmaf(2.f, go.w, -rx.w));
        rt2o = t2o;
        bXo[n] = pk4h(make_float4(fov * t2o.x, fov * t2o.y, fov * t2o.z, fov * t2o.w));
        *(uint2*)(bp + 3 * jstep) = pk4h(t2o);           // j3 raw
        float4 t2i = make_float4(fmaf(fiv2, gi.x, -rx.x), fmaf(fiv2, gi.y, -rx.y),
                                 fmaf(fiv2, gi.z, -rx.z), fmaf(fiv2, gi.w, -rx.w));
        bXi[n] = pk4h(t2i);
        *(uint2*)(bp + 4 * jstep) = pk4h(t2i);           // j4 raw
    }
    __syncthreads();
    // ph56: T3o = 2*sum(bXo) - T1o ; T3i = fiv2*sum(bXi) - T1o (quirk: both T1o)
    if (act) {
        float4 go = g8h((const char*)bXo, eo_s, e0o, e1o);
        float4 gi = g8h((const char*)bXi, eid_s, e0i, e1i);
        float4 t3o = make_float4(fmaf(2.f, go.x, -rt1o.x), fmaf(2.f, go.y, -rt1o.y),
                                 fmaf(2.f, go.z, -rt1o.z), fmaf(2.f, go.w, -rt1o.w));
        bA[n] = pk4h(make_float4(fov * t3o.x, fov * t3o.y, fov * t3o.z, fov * t3o.w));
        *(uint2*)(bp + 5 * jstep) = pk4h(t3o);           // j5 raw
        float4 t3i = make_float4(fmaf(fiv2, gi.x, -rt1o.x), fmaf(fiv2, gi.y, -rt1o.y),
                                 fmaf(fiv2, gi.z, -rt1o.z), fmaf(fiv2, gi.w, -rt1o.w));
        bB[n] = pk4h(t3i);
        *(uint2*)(bp + 6 * jstep) = pk4h(t3i);           // j6 raw
    }
    __syncthreads();
    // ph78: T4o = 2*sum(bA) - T2o ; T4i = fiv2*sum(bB) - T2o (quirk: both T2o)
    if (act) {
        float4 go = g8h((const char*)bA, eo_s, e0o, e1o);
        float4 gi = g8h((const char*)bB, eid_s, e0i, e1i);
        float4 t4o = make_float4(fmaf(2.f, go.x, -rt2o.x), fmaf(2.f, go.y, -rt2o.y),
                                 fmaf(2.f, go.z, -rt2o.z), fmaf(2.f, go.w, -rt2o.w));
        *(uint2*)(bp + 7 * jstep) = pk4h(t4o);           // j7
        float4 t4i = make_float4(fmaf(fiv2, gi.x, -rt2o.x), fmaf(fiv2, gi.y, -rt2o.y),
                                 fmaf(fiv2, gi.z, -rt2o.z), fmaf(fiv2, gi.w, -rt2o.w));
        *(uint2*)(bp + 8 * jstep) = pk4h(t4i);           // j8
    }
}

// ---------------- phase 2: GEMM (f16 MFMA) + gates + LN -> hnc ----------------

__global__ __launch_bounds__(256, 4) void k_gemm(const u16* __restrict__ basis,
        const u16* __restrict__ wt, const void* __restrict__ bz, const void* __restrict__ bh_,
        const void* __restrict__ lng, const void* __restrict__ lnb, u16* __restrict__ hnc,
        int rchp, int rchv, const int* __restrict__ flags) {
    union SM {
        struct { u16 A[2][4096]; u16 B[2][4096]; } st;   // 2 x (8KB+8KB)
        float heh[128 * 65];
    };
    __shared__ SM sm;
    __shared__ float sMu[128], sRs[128];
    __shared__ float sBz[64], sBh[64], sG[64], sB2[64];

    const int tid = threadIdx.x;
    if (tid < 64) {
        const int f32m = flags[0];
        sBz[tid] = ldf(bz, tid, f32m); sBh[tid] = ldf(bh_, tid, f32m);
        sG[tid] = ldf(lng, tid, f32m); sB2[tid] = ldf(lnb, tid, f32m);
    }
    const int lane = tid & 63, wv = tid >> 6;
    const int wr = wv >> 1, wc = wv & 1;
    const int m = lane & 15, q = lane >> 4;
    const int r0 = blockIdx.x * 128;

    f32x4_t acc[4][4];
    const f32x4_t zero = {0.f, 0.f, 0.f, 0.f};
    for (int mi = 0; mi < 4; ++mi)
        for (int ni = 0; ni < 4; ++ni) acc[mi][ni] = zero;

    auto stage = [&](int bb, int t) {
        const int j = t >> 1, hf = t & 1;
        #pragma unroll
        for (int p = 0; p < 2; ++p) {
            int lin = p * 256 + tid;
            int sbp = lin >> 6, rp = lin & 63;
            const u16* src = basis + ((size_t)((hf * 8 + sbp) * 9 + j) * rchp + r0 + rp * 2) * 4;
            gl_lds16(src, &sm.st.A[bb][lin * 8]);
        }
        #pragma unroll
        for (int p = 0; p < 2; ++p) {
            int lin = p * 256 + tid;
            int c = lin >> 2;
            int qq = ((lin & 3) ^ c ^ (c >> 2)) & 3;
            gl_lds16(wt + c * 576 + t * 32 + qq * 8, &sm.st.B[bb][lin * 8]);
        }
    };

    stage(0, 0);
    for (int t = 0; t < 18; ++t) {
        const int bb = t & 1;
        __syncthreads();                    // drains vmcnt -> buf bb ready
        if (t + 1 < 18) stage(bb ^ 1, t + 1);
        s16x8_t af[4], bfr[4];
        #pragma unroll
        for (int mi = 0; mi < 4; ++mi) {
            int r = wr * 64 + mi * 16 + m;
            s16x4_t lo = *(const s16x4_t*)&sm.st.A[bb][(2 * q) * 512 + r * 4];
            s16x4_t hi = *(const s16x4_t*)&sm.st.A[bb][(2 * q + 1) * 512 + r * 4];
            af[mi] = __builtin_shufflevector(lo, hi, 0, 1, 2, 3, 4, 5, 6, 7);
        }
        #pragma unroll
        for (int ni = 0; ni < 4; ++ni) {
            int c = (ni < 2) ? (wc * 32 + ni * 16 + m) : (64 + wc * 32 + (ni - 2) * 16 + m);
            int slot = (q ^ c ^ (c >> 2)) & 3;
            bfr[ni] = *(const s16x8_t*)&sm.st.B[bb][(c * 4 + slot) * 8];
        }
        #pragma unroll
        for (int mi = 0; mi < 4; ++mi)
            #pragma unroll
            for (int ni = 0; ni < 4; ++ni)
                acc[mi][ni] = __builtin_amdgcn_mfma_f32_16x16x32_f16(
                    __builtin_bit_cast(f16x8_t, af[mi]),
                    __builtin_bit_cast(f16x8_t, bfr[ni]), acc[mi][ni], 0, 0, 0);
    }
    __syncthreads();   // all ds_reads done before heh overwrites staging

    #pragma unroll
    for (int mi = 0; mi < 4; ++mi) {
        #pragma unroll
        for (int ni = 0; ni < 2; ++ni) {
            const int f = wc * 32 + ni * 16 + m;
            const float vbz = sBz[f], vbh = sBh[f];
            #pragma unroll
            for (int r = 0; r < 4; ++r) {
                const int rl = wr * 64 + mi * 16 + q * 4 + r;
                float zp = acc[mi][ni][r];
                float hp = acc[mi][ni + 2][r];
                zp = (zp == zp) ? zp : 0.f;
                hp = (hp == hp) ? hp : 0.f;
                zp = fminf(fmaxf(zp + vbz, -30.f), 30.f);
                hp = fminf(fmaxf(hp + vbh, -15.f), 15.f);
                const float z = __fdividef(1.f, 1.f + __expf(-zp));
                const float e2 = __expf(2.f * hp);
                const float ht = __fdividef(e2 - 1.f, e2 + 1.f);
                float h = (1.f - z) * ht;
                h = fmaxf(h, 0.f);
                sm.heh[rl * 65 + f] = h;
            }
        }
    }
    __syncthreads();
    if (tid < 128) {
        float sum = 0.f, ss = 0.f;
        #pragma unroll 8
        for (int f = 0; f < 64; ++f) {
            float v = sm.heh[tid * 65 + f];
            sum += v; ss += v * v;
        }
        float mu = sum * 0.015625f;
        float var = fmaxf(ss * 0.015625f - mu * mu, 0.f);
        sMu[tid] = mu;
        sRs[tid] = rsqrtf(var + 1e-5f);
    }
    __syncthreads();
    for (int idx = tid; idx < 128 * 64; idx += 256) {
        int rl = idx >> 6, f = idx & 63;
        if (r0 + rl < rchv) {
            float v = (sm.heh[rl * 65 + f] - sMu[rl]) * sRs[rl] * sG[f] + sB2[f];
            hnc[(size_t)(r0 + rl) * 64 + f] = f2bf(v);
        }
    }
}

// ---------------- phase 3: final linear, atomic accumulate into obuf[160] ----------------

__global__ __launch_bounds__(256) void k_lin_chunk(const u16* __restrict__ hnc,
        const void* __restrict__ lw, float* __restrict__ obuf, int s0, int chs,
        const int* __restrict__ flags) {
    const int tid = threadIdx.x;
    const int f32m = flags[0];
    float acc[NB][NC];
    #pragma unroll
    for (int b = 0; b < NB; ++b)
        #pragma unroll
        for (int c = 0; c < NC; ++c) acc[b][c] = 0.f;

    const int hi_s = s0 + chs - 1;
    for (int w = blockIdx.x * 256 + tid; w < TNF; w += LWG2 * 256) {
        const int t = w / 64000;
        int blo_n = s0 - t + 11;
        const int blo = (blo_n > 0) ? (blo_n / 12) : 0;
        const int bhi_n = hi_s - t;
        const int bhi = (bhi_n >= 0) ? (bhi_n / 12) : -1;
        if (bhi < blo) continue;
        float wvv[NC];
        if (f32m) {
            #pragma unroll
            for (int c = 0; c < NC; ++c) wvv[c] = ((const float*)lw)[(size_t)c * TNF + w];
        } else {
            #pragma unroll
            for (int c = 0; c < NC; ++c) wvv[c] = bf2f(((const u16*)lw)[(size_t)c * TNF + w]);
        }
        #pragma unroll
        for (int c = 0; c < NC; ++c) {
            float v = wvv[c];
            wvv[c] = (v == v && v > -1e30f && v < 1e30f) ? v : 0.f;
        }
        #pragma unroll
        for (int b = 0; b < NB; ++b) {
            if (b >= blo && b <= bhi) {
                const int sl = b * 12 + t - s0;
                const float h = bf2f(hnc[(size_t)sl * 64000 + (w - t * 64000)]);
                #pragma unroll
                for (int c = 0; c < NC; ++c) acc[b][c] = fmaf(h, wvv[c], acc[b][c]);
            }
        }
    }
    __shared__ float sRed[4][160];
    const int wvi = tid >> 6, lane = tid & 63;
    #pragma unroll
    for (int b = 0; b < NB; ++b)
        #pragma unroll
        for (int c = 0; c < NC; ++c) {
            float v = acc[b][c];
            #pragma unroll
            for (int off = 1; off < 64; off <<= 1) v += __shfl_xor(v, off, 64);
            if (lane == 0) sRed[wvi][b * NC + c] = v;
        }
    __syncthreads();
    if (tid < 160)
        atomicAdd(&obuf[tid], sRed[0][tid] + sRed[1][tid] + sRed[2][tid] + sRed[3][tid]);
}

__global__ void k_red(const float* __restrict__ obuf, const void* __restrict__ lb,
                      void* __restrict__ out, const int* __restrict__ flags) {
    const int o = threadIdx.x;
    const int f32m = flags[0];
    if (o < 160) {
        float s = obuf[o] + ldf(lb, o % NC, f32m);
        if (f32m) ((float*)out)[o] = s;
        else      ((u16*)out)[o] = f2bf(s);
    }
}

// ---------------- launch ----------------

extern "C" void kernel_launch(void* const* d_in, const int* in_sizes, int n_in,
                              void* d_out, int out_size, void* d_ws, size_t ws_size,
                              hipStream_t stream) {
    (void)in_sizes; (void)n_in; (void)out_size;
    const void* x   = d_in[0];
    const int*  ei  = (const int*)d_in[1];
    const void* Wz  = d_in[2];
    const void* bz  = d_in[3];
    const void* Wh  = d_in[6];
    const void* bh  = d_in[7];
    const void* lng = d_in[8];
    const void* lnb = d_in[9];
    const void* lw  = d_in[10];
    const void* lb  = d_in[11];

    char* ws = (char*)d_ws;
    size_t off = 0;
    auto alloc = [&](size_t bytes) -> void* {
        void* p = ws + off;
        off = (off + bytes + 255) & ~(size_t)255;
        return p;
    };
    int*   flags    = (int*)  alloc(64);
    u16*   wt       = (u16*)  alloc(128 * 576 * 2);
    int*   ints     = (int*)  alloc(4000 * 4);
    int*   ooffp    = (int*)  alloc(1024 * 4);
    int*   ioffp    = (int*)  alloc(1024 * 4);
    float* inv_o    = (float*)alloc(1000 * 4);
    float* inv_i    = (float*)alloc(1000 * 4);
    u16*   eo_s     = (u16*)  alloc((size_t)EPAD * 2);
    u16*   eid_s    = (u16*)  alloc((size_t)EPAD * 2);
    float* obuf     = (float*)alloc(160 * 4);

    // CHS capped at 96: basis (110 MB) stays L3-resident between k_cheb and
    // k_gemm, and k_cheb dispatches drop to ~88 us so the profiler's top-5
    // reveals the next-largest kernel (diagnostic for the ~307 us remainder).
    const int cand[] = {96, 64, 48, 32, 24, 16, 12, 8, 6, 4, 3, 2, 1};
    int CHS = 1, RCHP = 1024;
    for (int ci = 0; ci < 13; ++ci) {
        int c = cand[ci];
        int rchp = ((c * NN + 127) / 128) * 128;
        size_t need = (size_t)16 * 9 * rchp * 8 + (size_t)c * NN * FF * 2 + 8192;
        if (off + need <= ws_size) { CHS = c; RCHP = rchp; break; }
    }
    u16* basis = (u16*)alloc((size_t)16 * 9 * RCHP * 8);
    u16* hnc   = (u16*)alloc((size_t)CHS * NN * FF * 2);

    int* deg_out = ints;
    int* deg_in  = ints + 1000;
    int* cur     = ints + 2000;

    k_pre<<<160, 256, 0, stream>>>((const u16*)x, ei, flags, ints, obuf, eo_s, eid_s);
    k_deg<<<(EE + 255) / 256, 256, 0, stream>>>(ei, ints, flags);
    k_scan<<<1, 1024, 0, stream>>>(deg_in, deg_out, ooffp, ioffp, inv_o, inv_i);
    k_fill<<<(EE + 255) / 256, 256, 0, stream>>>(ei, ooffp, ioffp, cur, eo_s, eid_s, flags);
    k_wt<<<288, 256, 0, stream>>>(Wz, Wh, wt, flags);
    const int nchunk = SS / CHS;
    for (int ch = 0; ch < nchunk; ++ch) {
        k_cheb<<<CHS * 16, 1024, 0, stream>>>(x, eo_s, ooffp, eid_s, ioffp, inv_o, inv_i,
                                              basis, ch * CHS, RCHP, flags, CHS);
        k_gemm<<<RCHP / 128, 256, 0, stream>>>(basis, wt, bz, bh, lng, lnb, hnc,
                                               RCHP, CHS * NN, flags);
        k_lin_chunk<<<LWG2, 256, 0, stream>>>(hnc, lw, obuf, ch * CHS, CHS, flags);
    }
    k_red<<<1, 256, 0, stream>>>(obuf, lb, d_out, flags);
}

// Round 12
// 401.679 us; speedup vs baseline: 1.3842x; 1.3842x over previous
//
#include <hip/hip_runtime.h>

#define NN   1000
#define EE   16000
#define FF   64
#define SS   192
#define TNF  768000
#define NB   16
#define NC   10
#define LSPL 8     // slices per snapshot in k_lin (8000 words each)
#define EPAD 24576 // padded edge-list capacity (sum ceil(deg/8)*8 <= 23000)

typedef unsigned short u16;
typedef unsigned int   u32;
typedef float f32x4_t __attribute__((ext_vector_type(4)));
typedef short s16x4_t __attribute__((ext_vector_type(4)));
typedef short s16x8_t __attribute__((ext_vector_type(8)));
typedef _Float16 f16x2_t __attribute__((ext_vector_type(2)));
typedef _Float16 f16x8_t __attribute__((ext_vector_type(8)));

__device__ __forceinline__ float bf2f(u16 u) {
    return __uint_as_float(((u32)u) << 16);
}
__device__ __forceinline__ u16 f2bf(float f) {
    u32 u = __float_as_uint(f);
    u32 r = u + 0x7FFFu + ((u >> 16) & 1u);
    return (u16)(r >> 16);
}
__device__ __forceinline__ u16 f2h(float f) {
    _Float16 h = (_Float16)f;   // v_cvt_f16_f32 (RNE)
    return __builtin_bit_cast(unsigned short, h);
}
// flag-dispatched scalar float load (f32m: 1 = fp32 array, 0 = bf16 array)
__device__ __forceinline__ float ldf(const void* p, size_t i, int f32m) {
    return f32m ? ((const float*)p)[i] : bf2f(((const u16*)p)[i]);
}

// pack float4 -> 4 f16 in a uint2
__device__ __forceinline__ uint2 pk4h(float4 v) {
    uint2 p;
    p.x = (u32)f2h(v.x) | ((u32)f2h(v.y) << 16);
    p.y = (u32)f2h(v.z) | ((u32)f2h(v.w) << 16);
    return p;
}

// async global->LDS 16B copy (dest must be wave-uniform base + lane*16)
__device__ __forceinline__ void gl_lds16(const void* src, void* dst) {
    __builtin_amdgcn_global_load_lds(
        (const __attribute__((address_space(1))) unsigned int*)src,
        (__attribute__((address_space(3))) unsigned int*)dst, 16, 0, 0);
}

// ---------------- merged prep: detect + zero + edge-list prefill ----------------
// edge lists hold BYTE offsets (idx*8); dummy = 1000*8 = 8000 = 0x1F40
__global__ void k_pre(const u16* __restrict__ x, const int* __restrict__ ei,
                      int* __restrict__ flags, int* __restrict__ ints,
                      float* __restrict__ obuf, u16* __restrict__ eo_s,
                      u16* __restrict__ eid_s) {
    const int i = blockIdx.x * 256 + threadIdx.x;
    if (blockIdx.x == 0 && threadIdx.x < 64) {   // wave 0: parallel dtype detect
        const int lane = threadIdx.x;
        u16 u1 = x[2 * lane], u2 = x[2 * (lane + 64)];
        int e1 = (u1 >> 7) & 0xFF, e2 = (u2 >> 7) & 0xFF;
        int ok1 = (u1 == 0 || (e1 >= 100 && e1 <= 140)) ? 1 : 0;
        int ok2 = (u2 == 0 || (e2 >= 100 && e2 <= 140)) ? 1 : 0;
        unsigned long long b1 = __ballot(ok1), b2 = __ballot(ok2);
        int nzf = (lane < 32 && ei[2 * lane + 1] != 0) ? 1 : 0;
        unsigned long long b3 = __ballot(nzf);
        if (lane == 0) {
            int good = __popcll(b1) + __popcll(b2);
            flags[0] = (good < 96) ? 1 : 0;           // <75% plausible -> fp32
            flags[1] = (__popcll(b3) <= 4) ? 1 : 0;   // odd words all zero -> int64
        }
    }
    if (i < 4000) ints[i] = 0;
    if (i < 160) obuf[i] = 0.f;
    if (i < EPAD / 2) {
        ((u32*)eo_s)[i] = 0x1F401F40u;
        ((u32*)eid_s)[i] = 0x1F401F40u;
    }
}

__global__ void k_deg(const int* __restrict__ ei, int* __restrict__ deg,
                      const int* __restrict__ flags) {
    int e = blockIdx.x * 256 + threadIdx.x;
    const int sh = flags[1];
    if (e < EE) {
        int r = ei[(size_t)e << sh];
        int c = ei[(size_t)(EE + e) << sh];
        atomicAdd(&deg[r & 1023], 1);
        atomicAdd(&deg[NN + (c & 1023)], 1);
    }
}

// 8-padded CSR offsets + inverse degrees
__global__ __launch_bounds__(1024) void k_scan(const int* __restrict__ deg_in,
        const int* __restrict__ deg_out, int* __restrict__ ooffp, int* __restrict__ ioffp,
        float* __restrict__ inv_o, float* __restrict__ inv_i) {
    __shared__ int sa[1024], sb2[1024];
    const int t = threadIdx.x;
    for (int pass = 0; pass < 2; ++pass) {
        const int* deg = pass ? deg_out : deg_in;
        int* dst_off = pass ? ioffp : ooffp;
        sa[t] = (t < NN) ? ((deg[t] + 7) & ~7) : 0;
        __syncthreads();
        int* src = sa; int* dst = sb2;
        for (int offn = 1; offn < 1024; offn <<= 1) {
            int v = src[t];
            if (t >= offn) v += src[t - offn];
            dst[t] = v;
            __syncthreads();
            int* tmp = src; src = dst; dst = tmp;
        }
        if (t == 0) dst_off[0] = 0;
        if (t < NN) dst_off[t + 1] = src[t];
        __syncthreads();
    }
    if (t < NN) {
        inv_o[t] = 1.0f / (float)max(deg_out[t], 1);
        inv_i[t] = 1.0f / (float)max(deg_in[t], 1);
    }
}

__global__ void k_fill(const int* __restrict__ ei, const int* __restrict__ ooffp,
        const int* __restrict__ ioffp, int* __restrict__ cur,
        u16* __restrict__ eo_s, u16* __restrict__ eid_s,
        const int* __restrict__ flags) {
    int e = blockIdx.x * 256 + threadIdx.x;
    const int sh = flags[1];
    if (e < EE) {
        int r = ei[(size_t)e << sh] & 1023;
        int c = ei[(size_t)(EE + e) << sh] & 1023;
        int po = ooffp[c] + atomicAdd(&cur[c], 1);       // group by dst
        eo_s[po] = (u16)(r * 8);                          // byte offset
        int pi = ioffp[r] + atomicAdd(&cur[NN + r], 1);  // group by src
        eid_s[pi] = (u16)(c * 8);
    }
}

// Wt[col][kappa] (f16), kappa = j*64 + fi.  col<64 -> z (W_z), col>=64 -> h (W_h).
__global__ void k_wt(const void* __restrict__ Wz, const void* __restrict__ Wh,
                     u16* __restrict__ wt, const int* __restrict__ flags) {
    int idx = blockIdx.x * 256 + threadIdx.x;
    if (idx >= 128 * 576) return;
    const int f32m = flags[0];
    const int col = idx / 576;
    const int kk = idx - col * 576;
    const int j = kk >> 6, fi = kk & 63;
    const void* W = (col < 64) ? Wz : Wh;
    const int fo = col & 63;
    float v;
    if (j == 0) {
        v = ldf(W, (size_t)(0 * 128 + fi) * 64 + fo, f32m)
          + ldf(W, (size_t)(5 * 128 + fi) * 64 + fo, f32m);
    } else {
        const int d = (j & 1) ? 0 : 1;
        const int kq = (j + 1) >> 1;
        v = ldf(W, (size_t)((d * 5 + kq) * 128 + fi) * 64 + fo, f32m);
    }
    wt[col * 576 + kk] = f2h(v);
}

// ---------------- phase 1: Chebyshev basis (UNCHANGED source — control) ----------------
// basis: [sb(16)][j(9)][row(rchp)][f4(4)] f16

__device__ __forceinline__ float4 g8h(const char* __restrict__ S,
                                      const u16* __restrict__ lst, int e0, int e1) {
    f16x2_t a0 = {(_Float16)0, (_Float16)0}, a1 = a0, b0 = a0, b1 = a0;
    for (int e = e0; e < e1; e += 8) {
        uint4 w = *(const uint4*)(lst + e);   // 8 u16 byte-offsets, 16B aligned
        int i0 = w.x & 0xFFFF, i1 = w.x >> 16;
        int i2 = w.y & 0xFFFF, i3 = w.y >> 16;
        int i4 = w.z & 0xFFFF, i5 = w.z >> 16;
        int i6 = w.w & 0xFFFF, i7 = w.w >> 16;
        uint2 q0 = *(const uint2*)(S + i0), q1 = *(const uint2*)(S + i1);
        uint2 q2 = *(const uint2*)(S + i2), q3 = *(const uint2*)(S + i3);
        uint2 q4 = *(const uint2*)(S + i4), q5 = *(const uint2*)(S + i5);
        uint2 q6 = *(const uint2*)(S + i6), q7 = *(const uint2*)(S + i7);
        a0 += __builtin_bit_cast(f16x2_t, q0.x); a1 += __builtin_bit_cast(f16x2_t, q0.y);
        b0 += __builtin_bit_cast(f16x2_t, q1.x); b1 += __builtin_bit_cast(f16x2_t, q1.y);
        a0 += __builtin_bit_cast(f16x2_t, q2.x); a1 += __builtin_bit_cast(f16x2_t, q2.y);
        b0 += __builtin_bit_cast(f16x2_t, q3.x); b1 += __builtin_bit_cast(f16x2_t, q3.y);
        a0 += __builtin_bit_cast(f16x2_t, q4.x); a1 += __builtin_bit_cast(f16x2_t, q4.y);
        b0 += __builtin_bit_cast(f16x2_t, q5.x); b1 += __builtin_bit_cast(f16x2_t, q5.y);
        a0 += __builtin_bit_cast(f16x2_t, q6.x); a1 += __builtin_bit_cast(f16x2_t, q6.y);
        b0 += __builtin_bit_cast(f16x2_t, q7.x); b1 += __builtin_bit_cast(f16x2_t, q7.y);
    }
    float4 r;
    r.x = (float)a0.x + (float)b0.x;
    r.y = (float)a0.y + (float)b0.y;
    r.z = (float)a1.x + (float)b1.x;
    r.w = (float)a1.y + (float)b1.y;
    return r;
}

__global__ __launch_bounds__(1024) void k_cheb(const void* __restrict__ xv_,
        const u16* __restrict__ eo_s, const int* __restrict__ ooffp,
        const u16* __restrict__ eid_s, const int* __restrict__ ioffp,
        const float* __restrict__ inv_o, const float* __restrict__ inv_i,
        u16* __restrict__ basis, int s0, int rchp,
        const int* __restrict__ flags, int chs) {
    __shared__ uint2 bXo[1024], bXi[1024], bA[1024], bB[1024];
    const int sb = blockIdx.x / chs;
    const int slocal = blockIdx.x - sb * chs;
    const int s = s0 + slocal;
    const int n = threadIdx.x;
    const bool act = (n < NN);
    const int f32m = flags[0];
    int e0o = 0, e1o = 0, e0i = 0, e1i = 0;
    float fiv = 0.f, fov = 0.f;
    const int row = slocal * NN + n;
    if (act) {
        e0o = ooffp[n]; e1o = ooffp[n + 1];
        e0i = ioffp[n]; e1i = ioffp[n + 1];
        fiv = inv_i[n];
        fov = inv_o[n];
    }
    const float fiv2 = 2.f * fiv;
    u16* const bp = basis + (size_t)(sb * 9) * rchp * 4 + (size_t)row * 4;
    const size_t jstep = (size_t)rchp * 4;   // u16s per j-plane
    float4 rx, rt1o, rt2o;
    if (n >= NN) {   // zero the dummy slots (1000..1023) in all buffers
        const uint2 z = make_uint2(0u, 0u);
        bXo[n] = z; bXi[n] = z; bA[n] = z; bB[n] = z;
    }
    if (act) {
        const size_t xoff = ((size_t)s * NN + n) * FF + sb * 4;
        if (f32m) {
            rx = *(const float4*)((const float*)xv_ + xoff);
        } else {
            ushort4 u = *(const ushort4*)((const u16*)xv_ + xoff);
            rx = make_float4(bf2f(u.x), bf2f(u.y), bf2f(u.z), bf2f(u.w));
        }
        bXi[n] = pk4h(rx);
        bXo[n] = pk4h(make_float4(fov * rx.x, fov * rx.y, fov * rx.z, fov * rx.w));
        *(uint2*)bp = pk4h(rx);                          // j0 raw
    }
    __syncthreads();
    // ph12: T1o = sum(bXo) ; T1i = fiv * sum(bXi)
    if (act) {
        float4 go = g8h((const char*)bXo, eo_s, e0o, e1o);
        float4 gi = g8h((const char*)bXi, eid_s, e0i, e1i);
        rt1o = go;
        bA[n] = pk4h(make_float4(fov * go.x, fov * go.y, fov * go.z, fov * go.w));
        *(uint2*)(bp + jstep) = pk4h(go);                // j1 raw
        float4 t = make_float4(gi.x * fiv, gi.y * fiv, gi.z * fiv, gi.w * fiv);
        bB[n] = pk4h(t);
        *(uint2*)(bp + 2 * jstep) = pk4h(t);             // j2 raw
    }
    __syncthreads();
    // ph34: T2o = 2*sum(bA) - x ; T2i = fiv2*sum(bB) - x
    if (act) {
        float4 go = g8h((const char*)bA, eo_s, e0o, e1o);
        float4 gi = g8h((const char*)bB, eid_s, e0i, e1i);
        float4 t2o = make_float4(fmaf(2.f, go.x, -rx.x), fmaf(2.f, go.y, -rx.y),
                                 fmaf(2.f, go.z, -rx.z), fmaf(2.f, go.w, -rx.w));
        rt2o = t2o;
        bXo[n] = pk4h(make_float4(fov * t2o.x, fov * t2o.y, fov * t2o.z, fov * t2o.w));
        *(uint2*)(bp + 3 * jstep) = pk4h(t2o);           // j3 raw
        float4 t2i = make_float4(fmaf(fiv2, gi.x, -rx.x), fmaf(fiv2, gi.y, -rx.y),
                                 fmaf(fiv2, gi.z, -rx.z), fmaf(fiv2, gi.w, -rx.w));
        bXi[n] = pk4h(t2i);
        *(uint2*)(bp + 4 * jstep) = pk4h(t2i);           // j4 raw
    }
    __syncthreads();
    // ph56: T3o = 2*sum(bXo) - T1o ; T3i = fiv2*sum(bXi) - T1o (quirk: both T1o)
    if (act) {
        float4 go = g8h((const char*)bXo, eo_s, e0o, e1o);
        float4 gi = g8h((const char*)bXi, eid_s, e0i, e1i);
        float4 t3o = make_float4(fmaf(2.f, go.x, -rt1o.x), fmaf(2.f, go.y, -rt1o.y),
                                 fmaf(2.f, go.z, -rt1o.z), fmaf(2.f, go.w, -rt1o.w));
        bA[n] = pk4h(make_float4(fov * t3o.x, fov * t3o.y, fov * t3o.z, fov * t3o.w));
        *(uint2*)(bp + 5 * jstep) = pk4h(t3o);           // j5 raw
        float4 t3i = make_float4(fmaf(fiv2, gi.x, -rt1o.x), fmaf(fiv2, gi.y, -rt1o.y),
                                 fmaf(fiv2, gi.z, -rt1o.z), fmaf(fiv2, gi.w, -rt1o.w));
        bB[n] = pk4h(t3i);
        *(uint2*)(bp + 6 * jstep) = pk4h(t3i);           // j6 raw
    }
    __syncthreads();
    // ph78: T4o = 2*sum(bA) - T2o ; T4i = fiv2*sum(bB) - T2o (quirk: both T2o)
    if (act) {
        float4 go = g8h((const char*)bA, eo_s, e0o, e1o);
        float4 gi = g8h((const char*)bB, eid_s, e0i, e1i);
        float4 t4o = make_float4(fmaf(2.f, go.x, -rt2o.x), fmaf(2.f, go.y, -rt2o.y),
                                 fmaf(2.f, go.z, -rt2o.z), fmaf(2.f, go.w, -rt2o.w));
        *(uint2*)(bp + 7 * jstep) = pk4h(t4o);           // j7
        float4 t4i = make_float4(fmaf(fiv2, gi.x, -rt2o.x), fmaf(fiv2, gi.y, -rt2o.y),
                                 fmaf(fiv2, gi.z, -rt2o.z), fmaf(fiv2, gi.w, -rt2o.w));
        *(uint2*)(bp + 8 * jstep) = pk4h(t4i);           // j8
    }
}

// ---------------- phase 2: GEMM (f16 MFMA) + gates + LN -> hnc ----------------

__global__ __launch_bounds__(256, 4) void k_gemm(const u16* __restrict__ basis,
        const u16* __restrict__ wt, const void* __restrict__ bz, const void* __restrict__ bh_,
        const void* __restrict__ lng, const void* __restrict__ lnb, u16* __restrict__ hnc,
        int rchp, int rchv, const int* __restrict__ flags) {
    union SM {
        struct { u16 A[2][4096]; u16 B[2][4096]; } st;   // 2 x (8KB+8KB)
        float heh[128 * 65];
    };
    __shared__ SM sm;
    __shared__ float sMu[128], sRs[128];
    __shared__ float sBz[64], sBh[64], sG[64], sB2[64];

    const int tid = threadIdx.x;
    if (tid < 64) {
        const int f32m = flags[0];
        sBz[tid] = ldf(bz, tid, f32m); sBh[tid] = ldf(bh_, tid, f32m);
        sG[tid] = ldf(lng, tid, f32m); sB2[tid] = ldf(lnb, tid, f32m);
    }
    const int lane = tid & 63, wv = tid >> 6;
    const int wr = wv >> 1, wc = wv & 1;
    const int m = lane & 15, q = lane >> 4;
    const int r0 = blockIdx.x * 128;

    f32x4_t acc[4][4];
    const f32x4_t zero = {0.f, 0.f, 0.f, 0.f};
    for (int mi = 0; mi < 4; ++mi)
        for (int ni = 0; ni < 4; ++ni) acc[mi][ni] = zero;

    auto stage = [&](int bb, int t) {
        const int j = t >> 1, hf = t & 1;
        #pragma unroll
        for (int p = 0; p < 2; ++p) {
            int lin = p * 256 + tid;
            int sbp = lin >> 6, rp = lin & 63;
            const u16* src = basis + ((size_t)((hf * 8 + sbp) * 9 + j) * rchp + r0 + rp * 2) * 4;
            gl_lds16(src, &sm.st.A[bb][lin * 8]);
        }
        #pragma unroll
        for (int p = 0; p < 2; ++p) {
            int lin = p * 256 + tid;
            int c = lin >> 2;
            int qq = ((lin & 3) ^ c ^ (c >> 2)) & 3;
            gl_lds16(wt + c * 576 + t * 32 + qq * 8, &sm.st.B[bb][lin * 8]);
        }
    };

    stage(0, 0);
    for (int t = 0; t < 18; ++t) {
        const int bb = t & 1;
        __syncthreads();                    // drains vmcnt -> buf bb ready
        if (t + 1 < 18) stage(bb ^ 1, t + 1);
        s16x8_t af[4], bfr[4];
        #pragma unroll
        for (int mi = 0; mi < 4; ++mi) {
            int r = wr * 64 + mi * 16 + m;
            s16x4_t lo = *(const s16x4_t*)&sm.st.A[bb][(2 * q) * 512 + r * 4];
            s16x4_t hi = *(const s16x4_t*)&sm.st.A[bb][(2 * q + 1) * 512 + r * 4];
            af[mi] = __builtin_shufflevector(lo, hi, 0, 1, 2, 3, 4, 5, 6, 7);
        }
        #pragma unroll
        for (int ni = 0; ni < 4; ++ni) {
            int c = (ni < 2) ? (wc * 32 + ni * 16 + m) : (64 + wc * 32 + (ni - 2) * 16 + m);
            int slot = (q ^ c ^ (c >> 2)) & 3;
            bfr[ni] = *(const s16x8_t*)&sm.st.B[bb][(c * 4 + slot) * 8];
        }
        #pragma unroll
        for (int mi = 0; mi < 4; ++mi)
            #pragma unroll
            for (int ni = 0; ni < 4; ++ni)
                acc[mi][ni] = __builtin_amdgcn_mfma_f32_16x16x32_f16(
                    __builtin_bit_cast(f16x8_t, af[mi]),
                    __builtin_bit_cast(f16x8_t, bfr[ni]), acc[mi][ni], 0, 0, 0);
    }
    __syncthreads();   // all ds_reads done before heh overwrites staging

    #pragma unroll
    for (int mi = 0; mi < 4; ++mi) {
        #pragma unroll
        for (int ni = 0; ni < 2; ++ni) {
            const int f = wc * 32 + ni * 16 + m;
            const float vbz = sBz[f], vbh = sBh[f];
            #pragma unroll
            for (int r = 0; r < 4; ++r) {
                const int rl = wr * 64 + mi * 16 + q * 4 + r;
                float zp = acc[mi][ni][r];
                float hp = acc[mi][ni + 2][r];
                zp = (zp == zp) ? zp : 0.f;
                hp = (hp == hp) ? hp : 0.f;
                zp = fminf(fmaxf(zp + vbz, -30.f), 30.f);
                hp = fminf(fmaxf(hp + vbh, -15.f), 15.f);
                const float z = __fdividef(1.f, 1.f + __expf(-zp));
                const float e2 = __expf(2.f * hp);
                const float ht = __fdividef(e2 - 1.f, e2 + 1.f);
                float h = (1.f - z) * ht;
                h = fmaxf(h, 0.f);
                sm.heh[rl * 65 + f] = h;
            }
        }
    }
    __syncthreads();
    if (tid < 128) {
        float sum = 0.f, ss = 0.f;
        #pragma unroll 8
        for (int f = 0; f < 64; ++f) {
            float v = sm.heh[tid * 65 + f];
            sum += v; ss += v * v;
        }
        float mu = sum * 0.015625f;
        float var = fmaxf(ss * 0.015625f - mu * mu, 0.f);
        sMu[tid] = mu;
        sRs[tid] = rsqrtf(var + 1e-5f);
    }
    __syncthreads();
    for (int idx = tid; idx < 128 * 64; idx += 256) {
        int rl = idx >> 6, f = idx & 63;
        if (r0 + rl < rchv) {
            float v = (sm.heh[rl * 65 + f] - sMu[rl]) * sRs[rl] * sG[f] + sB2[f];
            hnc[(size_t)(r0 + rl) * 64 + f] = f2bf(v);
        }
    }
}

// ---------------- phase 3: final linear — snapshot-parallel dot products ----------------
// out[b][c] = sum_t dot(h[s=b*12+t], lw[c, t*64000:+64000]).
// Block = (chunk-local snapshot sl, slice q of 8000 words). Per-thread acc[10]
// (no spill), vec8 loads on h and all 10 lw streams, wave shuffle-reduce,
// one 10-lane atomicAdd per block (96 adds per output — trivial contention).

__global__ __launch_bounds__(256) void k_lin(const u16* __restrict__ hnc,
        const void* __restrict__ lw, float* __restrict__ obuf, int s0, int chs,
        const int* __restrict__ flags) {
    const int sl = blockIdx.x / LSPL;
    const int q  = blockIdx.x - sl * LSPL;
    const int s  = s0 + sl;
    const int b  = s / 12, t = s - b * 12;
    const int tid = threadIdx.x;
    const int f32m = flags[0];
    const int base = q * 8000;               // word offset within snapshot
    const u16* hrow = hnc + (size_t)sl * 64000 + base;
    const size_t lwoff = (size_t)t * 64000 + base;

    float acc[NC];
    #pragma unroll
    for (int c = 0; c < NC; ++c) acc[c] = 0.f;

    // 1000 vec8 positions per slice; 4 block-iterations of 256 threads
    #pragma unroll
    for (int it = 0; it < 4; ++it) {
        const int p = tid + it * 256;
        if (p < 1000) {
            const int w8 = p * 8;
            uint4 hv = *(const uint4*)(hrow + w8);
            float h0 = bf2f((u16)(hv.x & 0xFFFF)), h1 = bf2f((u16)(hv.x >> 16));
            float h2 = bf2f((u16)(hv.y & 0xFFFF)), h3 = bf2f((u16)(hv.y >> 16));
            float h4 = bf2f((u16)(hv.z & 0xFFFF)), h5 = bf2f((u16)(hv.z >> 16));
            float h6 = bf2f((u16)(hv.w & 0xFFFF)), h7 = bf2f((u16)(hv.w >> 16));
            #pragma unroll
            for (int c = 0; c < NC; ++c) {
                float v0, v1, v2, v3, v4, v5, v6, v7;
                if (f32m) {
                    const float* lp = (const float*)lw + (size_t)c * TNF + lwoff + w8;
                    float4 a = *(const float4*)lp;
                    float4 bv = *(const float4*)(lp + 4);
                    v0 = a.x; v1 = a.y; v2 = a.z; v3 = a.w;
                    v4 = bv.x; v5 = bv.y; v6 = bv.z; v7 = bv.w;
                } else {
                    const u16* lp = (const u16*)lw + (size_t)c * TNF + lwoff + w8;
                    uint4 a = *(const uint4*)lp;
                    v0 = bf2f((u16)(a.x & 0xFFFF)); v1 = bf2f((u16)(a.x >> 16));
                    v2 = bf2f((u16)(a.y & 0xFFFF)); v3 = bf2f((u16)(a.y >> 16));
                    v4 = bf2f((u16)(a.z & 0xFFFF)); v5 = bf2f((u16)(a.z >> 16));
                    v6 = bf2f((u16)(a.w & 0xFFFF)); v7 = bf2f((u16)(a.w >> 16));
                }
                v0 = (v0 == v0 && v0 > -1e30f && v0 < 1e30f) ? v0 : 0.f;
                v1 = (v1 == v1 && v1 > -1e30f && v1 < 1e30f) ? v1 : 0.f;
                v2 = (v2 == v2 && v2 > -1e30f && v2 < 1e30f) ? v2 : 0.f;
                v3 = (v3 == v3 && v3 > -1e30f && v3 < 1e30f) ? v3 : 0.f;
                v4 = (v4 == v4 && v4 > -1e30f && v4 < 1e30f) ? v4 : 0.f;
                v5 = (v5 == v5 && v5 > -1e30f && v5 < 1e30f) ? v5 : 0.f;
                v6 = (v6 == v6 && v6 > -1e30f && v6 < 1e30f) ? v6 : 0.f;
                v7 = (v7 == v7 && v7 > -1e30f && v7 < 1e30f) ? v7 : 0.f;
                float a0 = fmaf(h0, v0, fmaf(h1, v1, fmaf(h2, v2, h3 * v3)));
                float a1 = fmaf(h4, v4, fmaf(h5, v5, fmaf(h6, v6, h7 * v7)));
                acc[c] += a0 + a1;
            }
        }
    }

    __shared__ float sRed[4][NC];
    const int wvi = tid >> 6, lane = tid & 63;
    #pragma unroll
    for (int c = 0; c < NC; ++c) {
        float v = acc[c];
        #pragma unroll
        for (int off = 1; off < 64; off <<= 1) v += __shfl_xor(v, off, 64);
        if (lane == 0) sRed[wvi][c] = v;
    }
    __syncthreads();
    if (tid < NC)
        atomicAdd(&obuf[b * NC + tid],
                  sRed[0][tid] + sRed[1][tid] + sRed[2][tid] + sRed[3][tid]);
}

__global__ void k_red(const float* __restrict__ obuf, const void* __restrict__ lb,
                      void* __restrict__ out, const int* __restrict__ flags) {
    const int o = threadIdx.x;
    const int f32m = flags[0];
    if (o < 160) {
        float s = obuf[o] + ldf(lb, o % NC, f32m);
        if (f32m) ((float*)out)[o] = s;
        else      ((u16*)out)[o] = f2bf(s);
    }
}

// ---------------- launch ----------------

extern "C" void kernel_launch(void* const* d_in, const int* in_sizes, int n_in,
                              void* d_out, int out_size, void* d_ws, size_t ws_size,
                              hipStream_t stream) {
    (void)in_sizes; (void)n_in; (void)out_size;
    const void* x   = d_in[0];
    const int*  ei  = (const int*)d_in[1];
    const void* Wz  = d_in[2];
    const void* bz  = d_in[3];
    const void* Wh  = d_in[6];
    const void* bh  = d_in[7];
    const void* lng = d_in[8];
    const void* lnb = d_in[9];
    const void* lw  = d_in[10];
    const void* lb  = d_in[11];

    char* ws = (char*)d_ws;
    size_t off = 0;
    auto alloc = [&](size_t bytes) -> void* {
        void* p = ws + off;
        off = (off + bytes + 255) & ~(size_t)255;
        return p;
    };
    int*   flags    = (int*)  alloc(64);
    u16*   wt       = (u16*)  alloc(128 * 576 * 2);
    int*   ints     = (int*)  alloc(4000 * 4);
    int*   ooffp    = (int*)  alloc(1024 * 4);
    int*   ioffp    = (int*)  alloc(1024 * 4);
    float* inv_o    = (float*)alloc(1000 * 4);
    float* inv_i    = (float*)alloc(1000 * 4);
    u16*   eo_s     = (u16*)  alloc((size_t)EPAD * 2);
    u16*   eid_s    = (u16*)  alloc((size_t)EPAD * 2);
    float* obuf     = (float*)alloc(160 * 4);

    const int cand[] = {192, 96, 64, 48, 32, 24, 16, 12, 8, 6, 4, 3, 2, 1};
    int CHS = 1, RCHP = 1024;
    for (int ci = 0; ci < 14; ++ci) {
        int c = cand[ci];
        int rchp = ((c * NN + 127) / 128) * 128;
        size_t need = (size_t)16 * 9 * rchp * 8 + (size_t)c * NN * FF * 2 + 8192;
        if (off + need <= ws_size) { CHS = c; RCHP = rchp; break; }
    }
    u16* basis = (u16*)alloc((size_t)16 * 9 * RCHP * 8);
    u16* hnc   = (u16*)alloc((size_t)CHS * NN * FF * 2);

    int* deg_out = ints;
    int* deg_in  = ints + 1000;
    int* cur     = ints + 2000;

    k_pre<<<160, 256, 0, stream>>>((const u16*)x, ei, flags, ints, obuf, eo_s, eid_s);
    k_deg<<<(EE + 255) / 256, 256, 0, stream>>>(ei, ints, flags);
    k_scan<<<1, 1024, 0, stream>>>(deg_in, deg_out, ooffp, ioffp, inv_o, inv_i);
    k_fill<<<(EE + 255) / 256, 256, 0, stream>>>(ei, ooffp, ioffp, cur, eo_s, eid_s, flags);
    k_wt<<<288, 256, 0, stream>>>(Wz, Wh, wt, flags);
    const int nchunk = SS / CHS;
    for (int ch = 0; ch < nchunk; ++ch) {
        k_cheb<<<CHS * 16, 1024, 0, stream>>>(x, eo_s, ooffp, eid_s, ioffp, inv_o, inv_i,
                                              basis, ch * CHS, RCHP, flags, CHS);
        k_gemm<<<RCHP / 128, 256, 0, stream>>>(basis, wt, bz, bh, lng, lnb, hnc,
                                               RCHP, CHS * NN, flags);
        k_lin<<<CHS * LSPL, 256, 0, stream>>>(hnc, lw, obuf, ch * CHS, CHS, flags);
    }
    k_red<<<1, 256, 0, stream>>>(obuf, lb, d_out, flags);
}